// Round 8
// baseline (1611.577 us; speedup 1.0000x reference)
//
#include <hip/hip_runtime.h>
#include <hip/hip_fp16.h>

#define D 128

typedef _Float16 half8 __attribute__((ext_vector_type(8)));
typedef float floatx4 __attribute__((ext_vector_type(4)));

// ---------------- setup kernels ----------------

__global__ void k_zero(int* __restrict__ p, int n) {
    int i = blockIdx.x * 256 + threadIdx.x;
    if (i < n) p[i] = 0;
}

// count degrees AND record each edge's rank within its destination
__global__ void k_count(const int* __restrict__ dst, int* __restrict__ cnt,
                        int* __restrict__ rank, int e) {
    int i = blockIdx.x * 256 + threadIdx.x;
    if (i < e) rank[i] = atomicAdd(&cnt[dst[i]], 1);
}

// f32 row-major -> fp16 SLICE-MAJOR [8][N][16] convert.
// thread i: node = i>>3, slice = i&7. Reads coalesced 64B; writes 32B chunks
// that are contiguous-per-slice within a wave (8 nodes x 32B = 256B runs).
__global__ void k_f2h_s(const float* __restrict__ in, __half* __restrict__ out,
                        int n) {
    int i = blockIdx.x * 256 + threadIdx.x;
    if (i >= n * 8) return;
    int node = i >> 3, slice = i & 7;
    const float4* p = (const float4*)(in + (size_t)node * D + slice * 16);
    float4 a = p[0], b = p[1], c = p[2], d = p[3];
    __half2 h0 = __float22half2_rn(make_float2(a.x, a.y));
    __half2 h1 = __float22half2_rn(make_float2(a.z, a.w));
    __half2 h2 = __float22half2_rn(make_float2(b.x, b.y));
    __half2 h3 = __float22half2_rn(make_float2(b.z, b.w));
    __half2 h4 = __float22half2_rn(make_float2(c.x, c.y));
    __half2 h5 = __float22half2_rn(make_float2(c.z, c.w));
    __half2 h6 = __float22half2_rn(make_float2(d.x, d.y));
    __half2 h7 = __float22half2_rn(make_float2(d.z, d.w));
    uint4* o = (uint4*)(out + ((size_t)slice * n + node) * 16);
    uint4 o0, o1;
    o0.x = *(unsigned*)&h0; o0.y = *(unsigned*)&h1;
    o0.z = *(unsigned*)&h2; o0.w = *(unsigned*)&h3;
    o1.x = *(unsigned*)&h4; o1.y = *(unsigned*)&h5;
    o1.z = *(unsigned*)&h6; o1.w = *(unsigned*)&h7;
    o[0] = o0; o[1] = o1;
}

// ---- hierarchical scan (+ fused dinv) ----

__global__ __launch_bounds__(256) void k_scanA(const int* __restrict__ cnt,
                                               int* __restrict__ partials,
                                               float* __restrict__ dinv, int n) {
    __shared__ int s[256];
    int b = blockIdx.x, t = threadIdx.x;
    int i0 = b * 512 + t * 2;
    int v = 0;
    if (i0 < n) {
        int c0 = cnt[i0];
        v += c0;
        dinv[i0] = 1.0f / sqrtf((float)(c0 + 2));
    }
    if (i0 + 1 < n) {
        int c1 = cnt[i0 + 1];
        v += c1;
        dinv[i0 + 1] = 1.0f / sqrtf((float)(c1 + 2));
    }
    s[t] = v;
    __syncthreads();
    for (int off = 128; off > 0; off >>= 1) {
        if (t < off) s[t] += s[t + off];
        __syncthreads();
    }
    if (t == 0) partials[b] = s[0];
}

__global__ __launch_bounds__(512) void k_scanB(const int* __restrict__ partials,
                                               int* __restrict__ base,
                                               int* __restrict__ off_n, int nb) {
    __shared__ int s[512];
    int t = threadIdx.x;
    int v = (t < nb) ? partials[t] : 0;
    s[t] = v;
    __syncthreads();
    for (int off = 1; off < 512; off <<= 1) {
        int x = (t >= off) ? s[t - off] : 0;
        __syncthreads();
        s[t] += x;
        __syncthreads();
    }
    if (t < nb) base[t] = s[t] - v;          // exclusive
    if (t == nb - 1) off_n[0] = s[t];        // total = offsets[N]
}

__global__ __launch_bounds__(256) void k_scanC(const int* __restrict__ cnt,
                                               const int* __restrict__ base,
                                               int* __restrict__ offsets, int n) {
    __shared__ int s[256];
    int b = blockIdx.x, t = threadIdx.x;
    int i0 = b * 512 + t * 2;
    int v0 = (i0 < n) ? cnt[i0] : 0;
    int v1 = (i0 + 1 < n) ? cnt[i0 + 1] : 0;
    int sum = v0 + v1;
    s[t] = sum;
    __syncthreads();
    for (int off = 1; off < 256; off <<= 1) {
        int x = (t >= off) ? s[t - off] : 0;
        __syncthreads();
        s[t] += x;
        __syncthreads();
    }
    int excl = s[t] - sum + base[b];
    if (i0 < n) offsets[i0] = excl;
    if (i0 + 1 < n) offsets[i0 + 1] = excl + v0;
}

// packed CSR entry: .x = src, .y = bit-cast float norm; slot = offsets[dst]+rank
__global__ void k_fill(const int* __restrict__ src, const int* __restrict__ dst,
                       const int* __restrict__ rank, const int* __restrict__ offsets,
                       const float* __restrict__ dinv, int2* __restrict__ csr, int e) {
    int i = blockIdx.x * 256 + threadIdx.x;
    if (i < e) {
        int s = src[i];
        int d = dst[i];
        int pos = offsets[d] + rank[i];
        csr[pos] = make_int2(s, __float_as_int(dinv[s] * dinv[d]));
    }
}

// small 128x128 @ 128x128
__global__ __launch_bounds__(128) void k_wmm(const float* __restrict__ A,
                                             const float* __restrict__ B,
                                             float* __restrict__ Cm) {
    __shared__ float a[128];
    int r = blockIdx.x, d = threadIdx.x;
    a[d] = A[r * 128 + d];
    __syncthreads();
    float acc = 0.0f;
#pragma unroll 8
    for (int k = 0; k < 128; k++) acc += a[k] * B[k * 128 + d];
    Cm[r * 128 + d] = acc;
}

// blocks 0..127: Wtot = W1 @ W4.  block 128: bias chain.
__global__ __launch_bounds__(128) void k_wmm_bias(const float* __restrict__ W1,
                                                  const float* __restrict__ W4,
                                                  const float* __restrict__ W2,
                                                  const float* __restrict__ b1,
                                                  const float* __restrict__ b2,
                                                  float* __restrict__ Wtot,
                                                  float* __restrict__ cmat) {
    __shared__ float s[128];
    int d = threadIdx.x;
    if (blockIdx.x < 128) {
        int r = blockIdx.x;
        s[d] = W1[r * 128 + d];
        __syncthreads();
        float acc = 0.0f;
#pragma unroll 8
        for (int k = 0; k < 128; k++) acc += s[k] * W4[k * 128 + d];
        Wtot[r * 128 + d] = acc;
        return;
    }
    float v = b2[d];
    cmat[d] = v;
    for (int j = 1; j <= 3; j++) {
        s[d] = v;
        __syncthreads();
        float acc = 0.0f;
#pragma unroll 8
        for (int k = 0; k < 128; k++) acc += s[k] * W2[k * 128 + d];
        v = acc;
        cmat[j * 128 + d] = v;
        __syncthreads();
    }
    s[d] = b1[d];
    __syncthreads();
    float acc = 0.0f;
#pragma unroll 8
    for (int k = 0; k < 128; k++) acc += s[k] * W4[k * 128 + d];
    cmat[4 * 128 + d] = acc;
}

// pack Wtot into MFMA B-fragments, hi(fp16) + residual(fp16).
// frag(s,t): lane l, elem j holds W[s*32 + 8*(l>>4) + j][t*16 + (l&15)].
__global__ __launch_bounds__(256) void k_wpack(const float* __restrict__ Wtot,
                                               __half* __restrict__ pack) {
    int tid = blockIdx.x * 256 + threadIdx.x;   // 0..2047
    int l = tid & 63, t = (tid >> 6) & 7, s = tid >> 9;
    int col = t * 16 + (l & 15);
    int krow = s * 32 + 8 * (l >> 4);
#pragma unroll
    for (int j = 0; j < 8; j++) {
        float w = Wtot[(krow + j) * 128 + col];
        __half hh = __float2half(w);
        float rem = w - __half2float(hh);
        pack[(size_t)tid * 8 + j] = hh;
        pack[16384 + (size_t)tid * 8 + j] = __float2half(rem);
    }
}

// ---------------- matmul: O = Hh(sliced fp16) @ (Whi+Wlo) + bias + U C -----
// A-operand read from slice-major layout [8][nrows][16].
__global__ __launch_bounds__(256) void k_matmul(const __half* __restrict__ Hh,
                                                const __half* __restrict__ Wpack,
                                                float* __restrict__ O,
                                                const float* __restrict__ ucol,  // [4][n]
                                                const float* __restrict__ cmat,  // [5][128]
                                                int nrows) {
    const int t = threadIdx.x;
    const int lane = t & 63, wave = t >> 6;
    const int rows0 = blockIdx.x * 64 + wave * 16;
    const int lrow = lane & 15, lk = lane >> 4;

    float uu[4][4];
#pragma unroll
    for (int r = 0; r < 4; r++) {
        int row = rows0 + lk * 4 + r;
        if (row >= nrows) row = nrows - 1;     // clamped rows never stored
#pragma unroll
        for (int tt = 0; tt < 4; tt++) uu[tt][r] = ucol[(size_t)tt * nrows + row];
    }

    floatx4 acc[8];
#pragma unroll
    for (int tl = 0; tl < 8; tl++) {
        int col = tl * 16 + lrow;
        float c0 = cmat[col];
        float c1 = cmat[128 + col], c2 = cmat[256 + col];
        float c3 = cmat[384 + col], c4 = cmat[512 + col];
#pragma unroll
        for (int r = 0; r < 4; r++)
            acc[tl][r] = c0 + uu[0][r] * c1 + uu[1][r] * c2
                            + uu[2][r] * c3 + uu[3][r] * c4;
    }

    int arow = rows0 + lrow;
    if (arow >= nrows) arow = nrows - 1;       // feeds only unstored D-rows

#pragma unroll
    for (int s = 0; s < 4; s++) {
        // global k-cols s*32 + lk*8 .. +8 live in slice 2s+(lk>>1), off (lk&1)*8
        int slice = 2 * s + (lk >> 1);
        const __half* ap = Hh + ((size_t)slice * nrows + arow) * 16 + (lk & 1) * 8;
        half8 a = *reinterpret_cast<const half8*>(ap);
        const __half* wb = Wpack + (size_t)s * 4096 + (size_t)lane * 8;
#pragma unroll
        for (int tl = 0; tl < 8; tl++) {
            half8 bh = *reinterpret_cast<const half8*>(wb + (size_t)tl * 512);
            half8 bl = *reinterpret_cast<const half8*>(wb + (size_t)tl * 512 + 16384);
            acc[tl] = __builtin_amdgcn_mfma_f32_16x16x32_f16(a, bh, acc[tl], 0, 0, 0);
            acc[tl] = __builtin_amdgcn_mfma_f32_16x16x32_f16(a, bl, acc[tl], 0, 0, 0);
        }
    }

    // C/D layout (HW-verified): col = lane&15, row = (lane>>4)*4 + reg
#pragma unroll
    for (int r = 0; r < 4; r++) {
        int row = rows0 + lk * 4 + r;
        if (row < nrows) {
            float* orow = O + (size_t)row * 128 + lrow;
#pragma unroll
            for (int tl = 0; tl < 8; tl++) orow[tl * 16] = acc[tl][r];
        }
    }
}

// ---------------- sliced gather: O = A T ----------------
// T, O slice-major [8][n][16] fp16. slice = blockIdx&7 -> XCD-pinned via
// round-robin dispatch: per-XCD working set = 3.2MB slice (fits 4MB L2),
// killing the 8x compulsory refetch. One wave per (node, slice);
// lane = edge-group g (lane>>3) x col-pair p (lane&7); 8 edges/iter, 2x
// unrolled; stride-8 shfl reduction. u-chain (spmv) on slice 0 only.
template <bool WITH_U, bool IN_ROWMAJOR_F32>
__global__ __launch_bounds__(256) void k_gather_s(const void* __restrict__ Tv,
                                                  const int2* __restrict__ csr,
                                                  const int* __restrict__ offsets,
                                                  const float* __restrict__ dinv,
                                                  __half* __restrict__ Ov,
                                                  const float* __restrict__ uin,
                                                  float* __restrict__ uout, int n) {
    const int slice = blockIdx.x & 7;
    const int node = (blockIdx.x >> 3) * 4 + (threadIdx.x >> 6);
    if (node >= n) return;
    const int lane = threadIdx.x & 63;
    const int g = lane >> 3;         // edge sub-index 0..7
    const int p = lane & 7;          // col pair (cols 2p, 2p+1 of slice)
    const bool do_u = WITH_U && (slice == 0);

    const __half* Ts = (const __half*)Tv + (((size_t)slice * n) << 4) + (p << 1);
    const float*  Xs = (const float*)Tv + (size_t)(slice * 16 + p * 2);

    float dn = dinv[node];
    float sw = 2.0f * dn * dn;
    float a0 = 0.f, a1 = 0.f, uacc = 0.f;

    if (g == 0) {   // self loop
        if (IN_ROWMAJOR_F32) {
            float2 v = *(const float2*)(Xs + (size_t)node * D);
            a0 = sw * v.x; a1 = sw * v.y;
        } else {
            unsigned raw = *(const unsigned*)(Ts + ((size_t)node << 4));
            __half2 h = *reinterpret_cast<const __half2*>(&raw);
            a0 = sw * __low2float(h); a1 = sw * __high2float(h);
        }
        if (do_u && p == 0) uacc = sw * (uin ? uin[node] : 1.0f);
    }

    int e = offsets[node];
    const int e1 = offsets[node + 1];

    // main: 16 edges/iter (2 independent 8-edge groups)
    for (; e + 16 <= e1; e += 16) {
        int2 pa = csr[e + g];
        int2 pb = csr[e + 8 + g];
        float wa = __int_as_float(pa.y), wb = __int_as_float(pb.y);
        if (IN_ROWMAJOR_F32) {
            float2 va = *(const float2*)(Xs + (size_t)pa.x * D);
            float2 vb = *(const float2*)(Xs + (size_t)pb.x * D);
            a0 = fmaf(wa, va.x, a0); a1 = fmaf(wa, va.y, a1);
            a0 = fmaf(wb, vb.x, a0); a1 = fmaf(wb, vb.y, a1);
        } else {
            unsigned ra = *(const unsigned*)(Ts + ((size_t)pa.x << 4));
            unsigned rb = *(const unsigned*)(Ts + ((size_t)pb.x << 4));
            __half2 ha = *reinterpret_cast<const __half2*>(&ra);
            __half2 hb = *reinterpret_cast<const __half2*>(&rb);
            a0 = fmaf(wa, __low2float(ha), a0); a1 = fmaf(wa, __high2float(ha), a1);
            a0 = fmaf(wb, __low2float(hb), a0); a1 = fmaf(wb, __high2float(hb), a1);
        }
        if (do_u && p == 0) {
            uacc = fmaf(wa, uin ? uin[pa.x] : 1.0f, uacc);
            uacc = fmaf(wb, uin ? uin[pb.x] : 1.0f, uacc);
        }
    }
    // masked tail: up to 2 iterations of 8
    for (; e < e1; e += 8) {
        int idx = e + g;
        bool ok = idx < e1;
        int2 pa = csr[ok ? idx : e];
        float wa = ok ? __int_as_float(pa.y) : 0.0f;
        if (IN_ROWMAJOR_F32) {
            float2 va = *(const float2*)(Xs + (size_t)pa.x * D);
            a0 = fmaf(wa, va.x, a0); a1 = fmaf(wa, va.y, a1);
        } else {
            unsigned ra = *(const unsigned*)(Ts + ((size_t)pa.x << 4));
            __half2 ha = *reinterpret_cast<const __half2*>(&ra);
            a0 = fmaf(wa, __low2float(ha), a0); a1 = fmaf(wa, __high2float(ha), a1);
        }
        if (do_u && p == 0) uacc = fmaf(wa, uin ? uin[pa.x] : 1.0f, uacc);
    }

    // reduce over edge-groups (stride-8 lanes)
    a0 += __shfl_xor(a0, 8, 64);  a1 += __shfl_xor(a1, 8, 64);
    a0 += __shfl_xor(a0, 16, 64); a1 += __shfl_xor(a1, 16, 64);
    a0 += __shfl_xor(a0, 32, 64); a1 += __shfl_xor(a1, 32, 64);
    if (do_u) {
        uacc += __shfl_xor(uacc, 8, 64);
        uacc += __shfl_xor(uacc, 16, 64);
        uacc += __shfl_xor(uacc, 32, 64);
    }

    if (g == 0) {
        __half2 o = __float22half2_rn(make_float2(a0, a1));
        *(__half2*)(Ov + (((size_t)slice * n + node) << 4) + (p << 1)) = o;
        if (do_u && lane == 0) uout[node] = uacc;
    }
}

// ---------------- launch ----------------
// out = (A^5 x)(W1 W2^4) + b2 + sum_{j=1..3}(A^j 1)(b2 W2^j) + (A^4 1)(b1 W2^4)
// Intermediates fp16 slice-major [8][N][16]; XCD-pinned sliced gathers;
// MFMA matmul with W hi/lo split.

extern "C" void kernel_launch(void* const* d_in, const int* in_sizes, int n_in,
                              void* d_out, int out_size, void* d_ws, size_t ws_size,
                              hipStream_t stream) {
    const float* x  = (const float*)d_in[0];
    const int*   ei = (const int*)d_in[1];
    const float* W1 = (const float*)d_in[2];
    const float* b1 = (const float*)d_in[3];
    const float* W2 = (const float*)d_in[4];
    const float* b2 = (const float*)d_in[5];
    const int N = in_sizes[0] / D;
    const int E = in_sizes[1] / 2;
    float* out = (float*)d_out;

    char* ws = (char*)d_ws;
    size_t woff = 0;
    auto alloc = [&](size_t bytes) -> void* {
        void* p = ws + woff;
        woff = (woff + bytes + 15) & ~(size_t)15;
        return p;
    };
    __half* T16a    = (__half*)alloc((size_t)N * D * sizeof(__half));
    __half* T16b    = (__half*)alloc((size_t)N * D * sizeof(__half));
    int*   cnt      = (int*)  alloc((size_t)N * sizeof(int));
    int*   offsets  = (int*)  alloc((size_t)(N + 1) * sizeof(int));
    int*   rank     = (int*)  alloc((size_t)E * sizeof(int));
    float* dinv     = (float*)alloc((size_t)N * sizeof(float));
    int2*  csr      = (int2*) alloc((size_t)E * sizeof(int2));
    int*   partials = (int*)  alloc(1024 * sizeof(int));
    int*   base     = (int*)  alloc(1024 * sizeof(int));
    float* ucol     = (float*)alloc((size_t)4 * N * sizeof(float));   // [4][N]
    float* cmat     = (float*)alloc(5 * 128 * sizeof(float));         // [5][128]
    float* Wsq      = (float*)alloc(128 * 128 * sizeof(float));
    float* W4       = (float*)alloc(128 * 128 * sizeof(float));
    float* Wtot     = (float*)alloc(128 * 128 * sizeof(float));
    __half* Wpack   = (__half*)alloc(32768 * sizeof(__half));         // hi|lo frags
    size_t x16_bytes = (size_t)N * D * sizeof(__half);
    bool use_x16 = (woff + x16_bytes) <= ws_size;
    __half* X16 = use_x16 ? (__half*)alloc(x16_bytes) : nullptr;
    (void)n_in; (void)out_size;

    const int* e_src = ei;
    const int* e_dst = ei + E;
    const int NB = (N + 511) / 512;

    // --- CSR build (rank-based, no atomic in fill) ---
    k_zero<<<(N + 255) / 256, 256, 0, stream>>>(cnt, N);
    k_count<<<(E + 255) / 256, 256, 0, stream>>>(e_dst, cnt, rank, E);
    k_scanA<<<NB, 256, 0, stream>>>(cnt, partials, dinv, N);
    k_scanB<<<1, 512, 0, stream>>>(partials, base, offsets + N, NB);
    k_scanC<<<NB, 256, 0, stream>>>(cnt, base, offsets, N);
    k_fill<<<(E + 255) / 256, 256, 0, stream>>>(e_src, e_dst, rank, offsets,
                                                dinv, csr, E);

    // --- g = A^5 x (sliced fp16 ping-pong); u_j fused into gathers 1-4 ---
    const int GG = ((N + 3) / 4) * 8;
    if (use_x16) {
        k_f2h_s<<<(N * 8 + 255) / 256, 256, 0, stream>>>(x, X16, N);
        k_gather_s<true, false><<<GG, 256, 0, stream>>>(
            X16, csr, offsets, dinv, T16a, nullptr, ucol, N);
    } else {
        k_gather_s<true, true><<<GG, 256, 0, stream>>>(
            x, csr, offsets, dinv, T16a, nullptr, ucol, N);
    }
    k_gather_s<true,  false><<<GG, 256, 0, stream>>>(
        T16a, csr, offsets, dinv, T16b, ucol,         ucol + N,     N);
    k_gather_s<true,  false><<<GG, 256, 0, stream>>>(
        T16b, csr, offsets, dinv, T16a, ucol + N,     ucol + 2 * N, N);
    k_gather_s<true,  false><<<GG, 256, 0, stream>>>(
        T16a, csr, offsets, dinv, T16b, ucol + 2 * N, ucol + 3 * N, N);
    k_gather_s<false, false><<<GG, 256, 0, stream>>>(
        T16b, csr, offsets, dinv, T16a, nullptr,      nullptr,      N);

    // --- weight chain + pack ---
    k_wmm<<<128, 128, 0, stream>>>(W2, W2, Wsq);
    k_wmm<<<128, 128, 0, stream>>>(Wsq, Wsq, W4);
    k_wmm_bias<<<129, 128, 0, stream>>>(W1, W4, W2, b1, b2, Wtot, cmat);
    k_wpack<<<8, 256, 0, stream>>>(Wtot, Wpack);

    // --- out = T16a @ Wtot + b2 + U C  (MFMA, sliced A) ---
    k_matmul<<<(N + 63) / 64, 256, 0, stream>>>(T16a, Wpack, out, ucol, cmat, N);
}

// Round 9
// 937.751 us; speedup vs baseline: 1.7186x; 1.7186x over previous
//
#include <hip/hip_runtime.h>
#include <hip/hip_fp16.h>

#define D 128

typedef _Float16 half8 __attribute__((ext_vector_type(8)));
typedef float floatx4 __attribute__((ext_vector_type(4)));

// ---------------- helpers ----------------

// fused f16->f32 convert + FMA over 4 halves (pattern-matches v_fma_mix_f32)
__device__ inline void acc_h4(float& a0, float& a1, float& a2, float& a3,
                              float w, uint2 raw) {
    __half2 h01 = *reinterpret_cast<const __half2*>(&raw.x);
    __half2 h23 = *reinterpret_cast<const __half2*>(&raw.y);
    a0 = fmaf(w, __low2float(h01), a0);
    a1 = fmaf(w, __high2float(h01), a1);
    a2 = fmaf(w, __low2float(h23), a2);
    a3 = fmaf(w, __high2float(h23), a3);
}

// ---------------- setup kernels ----------------

__global__ void k_zero(int* __restrict__ p, int n) {
    int i = blockIdx.x * 256 + threadIdx.x;
    if (i < n) p[i] = 0;
}

// count degrees AND record each edge's rank within its destination
__global__ void k_count(const int* __restrict__ dst, int* __restrict__ cnt,
                        int* __restrict__ rank, int e) {
    int i = blockIdx.x * 256 + threadIdx.x;
    if (i < e) rank[i] = atomicAdd(&cnt[dst[i]], 1);
}

// f32 row-major -> fp16 SLICE-MAJOR [8][N][16] convert.
__global__ void k_f2h_s(const float* __restrict__ in, __half* __restrict__ out,
                        int n) {
    int i = blockIdx.x * 256 + threadIdx.x;
    if (i >= n * 8) return;
    int node = i >> 3, slice = i & 7;
    const float4* p = (const float4*)(in + (size_t)node * D + slice * 16);
    float4 a = p[0], b = p[1], c = p[2], d = p[3];
    __half2 h0 = __float22half2_rn(make_float2(a.x, a.y));
    __half2 h1 = __float22half2_rn(make_float2(a.z, a.w));
    __half2 h2 = __float22half2_rn(make_float2(b.x, b.y));
    __half2 h3 = __float22half2_rn(make_float2(b.z, b.w));
    __half2 h4 = __float22half2_rn(make_float2(c.x, c.y));
    __half2 h5 = __float22half2_rn(make_float2(c.z, c.w));
    __half2 h6 = __float22half2_rn(make_float2(d.x, d.y));
    __half2 h7 = __float22half2_rn(make_float2(d.z, d.w));
    uint4* o = (uint4*)(out + ((size_t)slice * n + node) * 16);
    uint4 o0, o1;
    o0.x = *(unsigned*)&h0; o0.y = *(unsigned*)&h1;
    o0.z = *(unsigned*)&h2; o0.w = *(unsigned*)&h3;
    o1.x = *(unsigned*)&h4; o1.y = *(unsigned*)&h5;
    o1.z = *(unsigned*)&h6; o1.w = *(unsigned*)&h7;
    o[0] = o0; o[1] = o1;
}

// ---- hierarchical scan (+ fused dinv) ----

__global__ __launch_bounds__(256) void k_scanA(const int* __restrict__ cnt,
                                               int* __restrict__ partials,
                                               float* __restrict__ dinv, int n) {
    __shared__ int s[256];
    int b = blockIdx.x, t = threadIdx.x;
    int i0 = b * 512 + t * 2;
    int v = 0;
    if (i0 < n) {
        int c0 = cnt[i0];
        v += c0;
        dinv[i0] = 1.0f / sqrtf((float)(c0 + 2));
    }
    if (i0 + 1 < n) {
        int c1 = cnt[i0 + 1];
        v += c1;
        dinv[i0 + 1] = 1.0f / sqrtf((float)(c1 + 2));
    }
    s[t] = v;
    __syncthreads();
    for (int off = 128; off > 0; off >>= 1) {
        if (t < off) s[t] += s[t + off];
        __syncthreads();
    }
    if (t == 0) partials[b] = s[0];
}

__global__ __launch_bounds__(512) void k_scanB(const int* __restrict__ partials,
                                               int* __restrict__ base,
                                               int* __restrict__ off_n, int nb) {
    __shared__ int s[512];
    int t = threadIdx.x;
    int v = (t < nb) ? partials[t] : 0;
    s[t] = v;
    __syncthreads();
    for (int off = 1; off < 512; off <<= 1) {
        int x = (t >= off) ? s[t - off] : 0;
        __syncthreads();
        s[t] += x;
        __syncthreads();
    }
    if (t < nb) base[t] = s[t] - v;          // exclusive
    if (t == nb - 1) off_n[0] = s[t];        // total = offsets[N]
}

__global__ __launch_bounds__(256) void k_scanC(const int* __restrict__ cnt,
                                               const int* __restrict__ base,
                                               int* __restrict__ offsets, int n) {
    __shared__ int s[256];
    int b = blockIdx.x, t = threadIdx.x;
    int i0 = b * 512 + t * 2;
    int v0 = (i0 < n) ? cnt[i0] : 0;
    int v1 = (i0 + 1 < n) ? cnt[i0 + 1] : 0;
    int sum = v0 + v1;
    s[t] = sum;
    __syncthreads();
    for (int off = 1; off < 256; off <<= 1) {
        int x = (t >= off) ? s[t - off] : 0;
        __syncthreads();
        s[t] += x;
        __syncthreads();
    }
    int excl = s[t] - sum + base[b];
    if (i0 < n) offsets[i0] = excl;
    if (i0 + 1 < n) offsets[i0 + 1] = excl + v0;
}

// packed CSR entry: .x = src, .y = bit-cast float norm; slot = offsets[dst]+rank
__global__ void k_fill(const int* __restrict__ src, const int* __restrict__ dst,
                       const int* __restrict__ rank, const int* __restrict__ offsets,
                       const float* __restrict__ dinv, int2* __restrict__ csr, int e) {
    int i = blockIdx.x * 256 + threadIdx.x;
    if (i < e) {
        int s = src[i];
        int d = dst[i];
        int pos = offsets[d] + rank[i];
        csr[pos] = make_int2(s, __float_as_int(dinv[s] * dinv[d]));
    }
}

// small 128x128 @ 128x128
__global__ __launch_bounds__(128) void k_wmm(const float* __restrict__ A,
                                             const float* __restrict__ B,
                                             float* __restrict__ Cm) {
    __shared__ float a[128];
    int r = blockIdx.x, d = threadIdx.x;
    a[d] = A[r * 128 + d];
    __syncthreads();
    float acc = 0.0f;
#pragma unroll 8
    for (int k = 0; k < 128; k++) acc += a[k] * B[k * 128 + d];
    Cm[r * 128 + d] = acc;
}

// blocks 0..127: Wtot = W1 @ W4.  block 128: bias chain.
__global__ __launch_bounds__(128) void k_wmm_bias(const float* __restrict__ W1,
                                                  const float* __restrict__ W4,
                                                  const float* __restrict__ W2,
                                                  const float* __restrict__ b1,
                                                  const float* __restrict__ b2,
                                                  float* __restrict__ Wtot,
                                                  float* __restrict__ cmat) {
    __shared__ float s[128];
    int d = threadIdx.x;
    if (blockIdx.x < 128) {
        int r = blockIdx.x;
        s[d] = W1[r * 128 + d];
        __syncthreads();
        float acc = 0.0f;
#pragma unroll 8
        for (int k = 0; k < 128; k++) acc += s[k] * W4[k * 128 + d];
        Wtot[r * 128 + d] = acc;
        return;
    }
    float v = b2[d];
    cmat[d] = v;
    for (int j = 1; j <= 3; j++) {
        s[d] = v;
        __syncthreads();
        float acc = 0.0f;
#pragma unroll 8
        for (int k = 0; k < 128; k++) acc += s[k] * W2[k * 128 + d];
        v = acc;
        cmat[j * 128 + d] = v;
        __syncthreads();
    }
    s[d] = b1[d];
    __syncthreads();
    float acc = 0.0f;
#pragma unroll 8
    for (int k = 0; k < 128; k++) acc += s[k] * W4[k * 128 + d];
    cmat[4 * 128 + d] = acc;
}

// pack Wtot into MFMA B-fragments, hi(fp16) + residual(fp16).
__global__ __launch_bounds__(256) void k_wpack(const float* __restrict__ Wtot,
                                               __half* __restrict__ pack) {
    int tid = blockIdx.x * 256 + threadIdx.x;   // 0..2047
    int l = tid & 63, t = (tid >> 6) & 7, s = tid >> 9;
    int col = t * 16 + (l & 15);
    int krow = s * 32 + 8 * (l >> 4);
#pragma unroll
    for (int j = 0; j < 8; j++) {
        float w = Wtot[(krow + j) * 128 + col];
        __half hh = __float2half(w);
        float rem = w - __half2float(hh);
        pack[(size_t)tid * 8 + j] = hh;
        pack[16384 + (size_t)tid * 8 + j] = __float2half(rem);
    }
}

// ---------------- matmul: O = Hh(sliced fp16) @ (Whi+Wlo) + bias + U C -----
__global__ __launch_bounds__(256) void k_matmul(const __half* __restrict__ Hh,
                                                const __half* __restrict__ Wpack,
                                                float* __restrict__ O,
                                                const float* __restrict__ ucol,  // [4][n]
                                                const float* __restrict__ cmat,  // [5][128]
                                                int nrows) {
    const int t = threadIdx.x;
    const int lane = t & 63, wave = t >> 6;
    const int rows0 = blockIdx.x * 64 + wave * 16;
    const int lrow = lane & 15, lk = lane >> 4;

    float uu[4][4];
#pragma unroll
    for (int r = 0; r < 4; r++) {
        int row = rows0 + lk * 4 + r;
        if (row >= nrows) row = nrows - 1;     // clamped rows never stored
#pragma unroll
        for (int tt = 0; tt < 4; tt++) uu[tt][r] = ucol[(size_t)tt * nrows + row];
    }

    floatx4 acc[8];
#pragma unroll
    for (int tl = 0; tl < 8; tl++) {
        int col = tl * 16 + lrow;
        float c0 = cmat[col];
        float c1 = cmat[128 + col], c2 = cmat[256 + col];
        float c3 = cmat[384 + col], c4 = cmat[512 + col];
#pragma unroll
        for (int r = 0; r < 4; r++)
            acc[tl][r] = c0 + uu[0][r] * c1 + uu[1][r] * c2
                            + uu[2][r] * c3 + uu[3][r] * c4;
    }

    int arow = rows0 + lrow;
    if (arow >= nrows) arow = nrows - 1;       // feeds only unstored D-rows

#pragma unroll
    for (int s = 0; s < 4; s++) {
        // global k-cols s*32 + lk*8 .. +8 live in slice 2s+(lk>>1), off (lk&1)*8
        int slice = 2 * s + (lk >> 1);
        const __half* ap = Hh + ((size_t)slice * nrows + arow) * 16 + (lk & 1) * 8;
        half8 a = *reinterpret_cast<const half8*>(ap);
        const __half* wb = Wpack + (size_t)s * 4096 + (size_t)lane * 8;
#pragma unroll
        for (int tl = 0; tl < 8; tl++) {
            half8 bh = *reinterpret_cast<const half8*>(wb + (size_t)tl * 512);
            half8 bl = *reinterpret_cast<const half8*>(wb + (size_t)tl * 512 + 16384);
            acc[tl] = __builtin_amdgcn_mfma_f32_16x16x32_f16(a, bh, acc[tl], 0, 0, 0);
            acc[tl] = __builtin_amdgcn_mfma_f32_16x16x32_f16(a, bl, acc[tl], 0, 0, 0);
        }
    }

    // C/D layout (HW-verified): col = lane&15, row = (lane>>4)*4 + reg
#pragma unroll
    for (int r = 0; r < 4; r++) {
        int row = rows0 + lk * 4 + r;
        if (row < nrows) {
            float* orow = O + (size_t)row * 128 + lrow;
#pragma unroll
            for (int tl = 0; tl < 8; tl++) orow[tl * 16] = acc[tl][r];
        }
    }
}

// ---------------- sliced gather: O = A T ----------------
// T, O slice-major [8][n][16] fp16; slice = blockIdx&7 (XCD-pinned via
// round-robin) so per-XCD working set = 3.2MB (fits 4MB L2) — keeps round-8's
// validated FETCH win (275->~85MB). Execution geometry fixed vs round 8:
// 8 NODES PER WAVE (waves back to 100k, prologue amortized 8x) and 8B/lane
// loads (512B per load instruction). lane = n_sub(3b) x g(1b) x q(2b):
// per node 2 edges in flight x 4 lanes x 8B; 2x unrolled. Per-lane loop
// bounds diverge across the 8 nodes (max-degree trips) — issue slots are
// cheap here. Consecutive nodes => contiguous csr window per wave.
template <bool WITH_U, bool IN_ROWMAJOR_F32>
__global__ __launch_bounds__(256) void k_gather_s(const void* __restrict__ Tv,
                                                  const int2* __restrict__ csr,
                                                  const int* __restrict__ offsets,
                                                  const float* __restrict__ dinv,
                                                  __half* __restrict__ Ov,
                                                  const float* __restrict__ uin,
                                                  float* __restrict__ uout, int nn) {
    const int slice = blockIdx.x & 7;
    const int lane = threadIdx.x & 63;
    const int wv = threadIdx.x >> 6;
    const int n_sub = lane >> 3;        // 0..7 node within wave
    const int g = (lane >> 2) & 1;      // edge-pair bit
    const int q = lane & 3;             // col quad (cols 4q..4q+3 of slice)
    int node = (blockIdx.x >> 3) * 32 + wv * 8 + n_sub;
    const bool active = node < nn;
    if (!active) node = nn - 1;
    const bool do_u = WITH_U && (slice == 0) && (q == 0);

    const __half* Ts = (const __half*)Tv + (((size_t)slice * nn) << 4) + (q << 2);
    const float*  Xs = (const float*)Tv + (size_t)(slice * 16 + q * 4);

    float dn = dinv[node];
    float sw = 2.0f * dn * dn;
    float a0 = 0.f, a1 = 0.f, a2 = 0.f, a3 = 0.f, uacc = 0.f;

    if (g == 0 && active) {   // self loop
        if (IN_ROWMAJOR_F32) {
            float4 v = *(const float4*)(Xs + (size_t)node * D);
            a0 = sw * v.x; a1 = sw * v.y; a2 = sw * v.z; a3 = sw * v.w;
        } else {
            uint2 r = *(const uint2*)(Ts + ((size_t)node << 4));
            acc_h4(a0, a1, a2, a3, sw, r);
        }
        if (do_u) uacc = sw * (uin ? uin[node] : 1.0f);
    }

    const int e1 = active ? offsets[node + 1] : 0;
    int ee = (active ? offsets[node] : 0) + g;

    // 2 edges per lane in flight
    for (; ee + 2 < e1; ee += 4) {
        int2 pa = csr[ee];
        int2 pb = csr[ee + 2];
        float wa = __int_as_float(pa.y), wb = __int_as_float(pb.y);
        if (IN_ROWMAJOR_F32) {
            float4 va = *(const float4*)(Xs + (size_t)pa.x * D);
            float4 vb = *(const float4*)(Xs + (size_t)pb.x * D);
            a0 = fmaf(wa, va.x, a0); a1 = fmaf(wa, va.y, a1);
            a2 = fmaf(wa, va.z, a2); a3 = fmaf(wa, va.w, a3);
            a0 = fmaf(wb, vb.x, a0); a1 = fmaf(wb, vb.y, a1);
            a2 = fmaf(wb, vb.z, a2); a3 = fmaf(wb, vb.w, a3);
        } else {
            uint2 ra = *(const uint2*)(Ts + ((size_t)pa.x << 4));
            uint2 rb = *(const uint2*)(Ts + ((size_t)pb.x << 4));
            acc_h4(a0, a1, a2, a3, wa, ra);
            acc_h4(a0, a1, a2, a3, wb, rb);
        }
        if (do_u) {
            uacc = fmaf(wa, uin ? uin[pa.x] : 1.0f, uacc);
            uacc = fmaf(wb, uin ? uin[pb.x] : 1.0f, uacc);
        }
    }
    if (ee < e1) {
        int2 pa = csr[ee];
        float wa = __int_as_float(pa.y);
        if (IN_ROWMAJOR_F32) {
            float4 va = *(const float4*)(Xs + (size_t)pa.x * D);
            a0 = fmaf(wa, va.x, a0); a1 = fmaf(wa, va.y, a1);
            a2 = fmaf(wa, va.z, a2); a3 = fmaf(wa, va.w, a3);
        } else {
            uint2 ra = *(const uint2*)(Ts + ((size_t)pa.x << 4));
            acc_h4(a0, a1, a2, a3, wa, ra);
        }
        if (do_u) uacc = fmaf(wa, uin ? uin[pa.x] : 1.0f, uacc);
    }

    // reduce over the g bit (lane ^ 4)
    a0 += __shfl_xor(a0, 4, 64);
    a1 += __shfl_xor(a1, 4, 64);
    a2 += __shfl_xor(a2, 4, 64);
    a3 += __shfl_xor(a3, 4, 64);
    if (WITH_U) uacc += __shfl_xor(uacc, 4, 64);

    if (g == 0 && active) {
        __half2 o01 = __float22half2_rn(make_float2(a0, a1));
        __half2 o23 = __float22half2_rn(make_float2(a2, a3));
        uint2 o;
        o.x = *(unsigned*)&o01; o.y = *(unsigned*)&o23;
        *(uint2*)(Ov + (((size_t)slice * nn + node) << 4) + (q << 2)) = o;
        if (do_u) uout[node] = uacc;
    }
}

// ---------------- launch ----------------
// out = (A^5 x)(W1 W2^4) + b2 + sum_{j=1..3}(A^j 1)(b2 W2^j) + (A^4 1)(b1 W2^4)

extern "C" void kernel_launch(void* const* d_in, const int* in_sizes, int n_in,
                              void* d_out, int out_size, void* d_ws, size_t ws_size,
                              hipStream_t stream) {
    const float* x  = (const float*)d_in[0];
    const int*   ei = (const int*)d_in[1];
    const float* W1 = (const float*)d_in[2];
    const float* b1 = (const float*)d_in[3];
    const float* W2 = (const float*)d_in[4];
    const float* b2 = (const float*)d_in[5];
    const int N = in_sizes[0] / D;
    const int E = in_sizes[1] / 2;
    float* out = (float*)d_out;

    char* ws = (char*)d_ws;
    size_t woff = 0;
    auto alloc = [&](size_t bytes) -> void* {
        void* p = ws + woff;
        woff = (woff + bytes + 15) & ~(size_t)15;
        return p;
    };
    __half* T16a    = (__half*)alloc((size_t)N * D * sizeof(__half));
    __half* T16b    = (__half*)alloc((size_t)N * D * sizeof(__half));
    int*   cnt      = (int*)  alloc((size_t)N * sizeof(int));
    int*   offsets  = (int*)  alloc((size_t)(N + 1) * sizeof(int));
    int*   rank     = (int*)  alloc((size_t)E * sizeof(int));
    float* dinv     = (float*)alloc((size_t)N * sizeof(float));
    int2*  csr      = (int2*) alloc((size_t)E * sizeof(int2));
    int*   partials = (int*)  alloc(1024 * sizeof(int));
    int*   base     = (int*)  alloc(1024 * sizeof(int));
    float* ucol     = (float*)alloc((size_t)4 * N * sizeof(float));   // [4][N]
    float* cmat     = (float*)alloc(5 * 128 * sizeof(float));         // [5][128]
    float* Wsq      = (float*)alloc(128 * 128 * sizeof(float));
    float* W4       = (float*)alloc(128 * 128 * sizeof(float));
    float* Wtot     = (float*)alloc(128 * 128 * sizeof(float));
    __half* Wpack   = (__half*)alloc(32768 * sizeof(__half));         // hi|lo frags
    size_t x16_bytes = (size_t)N * D * sizeof(__half);
    bool use_x16 = (woff + x16_bytes) <= ws_size;
    __half* X16 = use_x16 ? (__half*)alloc(x16_bytes) : nullptr;
    (void)n_in; (void)out_size;

    const int* e_src = ei;
    const int* e_dst = ei + E;
    const int NB = (N + 511) / 512;

    // --- CSR build (rank-based, no atomic in fill) ---
    k_zero<<<(N + 255) / 256, 256, 0, stream>>>(cnt, N);
    k_count<<<(E + 255) / 256, 256, 0, stream>>>(e_dst, cnt, rank, E);
    k_scanA<<<NB, 256, 0, stream>>>(cnt, partials, dinv, N);
    k_scanB<<<1, 512, 0, stream>>>(partials, base, offsets + N, NB);
    k_scanC<<<NB, 256, 0, stream>>>(cnt, base, offsets, N);
    k_fill<<<(E + 255) / 256, 256, 0, stream>>>(e_src, e_dst, rank, offsets,
                                                dinv, csr, E);

    // --- g = A^5 x (sliced fp16 ping-pong); u_j fused into gathers 1-4 ---
    const int GG = ((N + 31) / 32) * 8;
    if (use_x16) {
        k_f2h_s<<<(N * 8 + 255) / 256, 256, 0, stream>>>(x, X16, N);
        k_gather_s<true, false><<<GG, 256, 0, stream>>>(
            X16, csr, offsets, dinv, T16a, nullptr, ucol, N);
    } else {
        k_gather_s<true, true><<<GG, 256, 0, stream>>>(
            x, csr, offsets, dinv, T16a, nullptr, ucol, N);
    }
    k_gather_s<true,  false><<<GG, 256, 0, stream>>>(
        T16a, csr, offsets, dinv, T16b, ucol,         ucol + N,     N);
    k_gather_s<true,  false><<<GG, 256, 0, stream>>>(
        T16b, csr, offsets, dinv, T16a, ucol + N,     ucol + 2 * N, N);
    k_gather_s<true,  false><<<GG, 256, 0, stream>>>(
        T16a, csr, offsets, dinv, T16b, ucol + 2 * N, ucol + 3 * N, N);
    k_gather_s<false, false><<<GG, 256, 0, stream>>>(
        T16b, csr, offsets, dinv, T16a, nullptr,      nullptr,      N);

    // --- weight chain + pack ---
    k_wmm<<<128, 128, 0, stream>>>(W2, W2, Wsq);
    k_wmm<<<128, 128, 0, stream>>>(Wsq, Wsq, W4);
    k_wmm_bias<<<129, 128, 0, stream>>>(W1, W4, W2, b1, b2, Wtot, cmat);
    k_wpack<<<8, 256, 0, stream>>>(Wtot, Wpack);

    // --- out = T16a @ Wtot + b2 + U C  (MFMA, sliced A) ---
    k_matmul<<<(N + 63) / 64, 256, 0, stream>>>(T16a, Wpack, out, ucol, cmat, N);
}

// Round 10
// 662.094 us; speedup vs baseline: 2.4341x; 1.4163x over previous
//
#include <hip/hip_runtime.h>
#include <hip/hip_fp16.h>

#define D 128

typedef _Float16 half8 __attribute__((ext_vector_type(8)));
typedef float floatx4 __attribute__((ext_vector_type(4)));

// ---------------- helpers ----------------

// fused f16->f32 convert + FMA (pattern-matches v_fma_mix_f32)
__device__ inline void acc_h4(float& ax, float& ay, float& az, float& aw,
                              float w, uint2 raw) {
    __half2 h01 = *reinterpret_cast<const __half2*>(&raw.x);
    __half2 h23 = *reinterpret_cast<const __half2*>(&raw.y);
    ax = fmaf(w, __low2float(h01), ax);
    ay = fmaf(w, __high2float(h01), ay);
    az = fmaf(w, __low2float(h23), az);
    aw = fmaf(w, __high2float(h23), aw);
}

// ---------------- setup kernels ----------------

__global__ void k_zero(int* __restrict__ p, int n) {
    int i = blockIdx.x * 256 + threadIdx.x;
    if (i < n) p[i] = 0;
}

// count degrees AND record each edge's rank within its destination
__global__ void k_count(const int* __restrict__ dst, int* __restrict__ cnt,
                        int* __restrict__ rank, int e) {
    int i = blockIdx.x * 256 + threadIdx.x;
    if (i < e) rank[i] = atomicAdd(&cnt[dst[i]], 1);
}

// f32 -> fp16 streaming convert (8 elems/thread), row-major
__global__ void k_f2h(const float* __restrict__ in, __half* __restrict__ out, int n8) {
    int i = blockIdx.x * 256 + threadIdx.x;
    if (i < n8) {
        const float4* p = (const float4*)in + (size_t)i * 2;
        float4 a = p[0], b = p[1];
        __half2 h0 = __float22half2_rn(make_float2(a.x, a.y));
        __half2 h1 = __float22half2_rn(make_float2(a.z, a.w));
        __half2 h2 = __float22half2_rn(make_float2(b.x, b.y));
        __half2 h3 = __float22half2_rn(make_float2(b.z, b.w));
        uint4 o;
        o.x = *(unsigned*)&h0; o.y = *(unsigned*)&h1;
        o.z = *(unsigned*)&h2; o.w = *(unsigned*)&h3;
        ((uint4*)out)[i] = o;
    }
}

// ---- hierarchical scan (+ fused dinv) ----

__global__ __launch_bounds__(256) void k_scanA(const int* __restrict__ cnt,
                                               int* __restrict__ partials,
                                               float* __restrict__ dinv, int n) {
    __shared__ int s[256];
    int b = blockIdx.x, t = threadIdx.x;
    int i0 = b * 512 + t * 2;
    int v = 0;
    if (i0 < n) {
        int c0 = cnt[i0];
        v += c0;
        dinv[i0] = 1.0f / sqrtf((float)(c0 + 2));
    }
    if (i0 + 1 < n) {
        int c1 = cnt[i0 + 1];
        v += c1;
        dinv[i0 + 1] = 1.0f / sqrtf((float)(c1 + 2));
    }
    s[t] = v;
    __syncthreads();
    for (int off = 128; off > 0; off >>= 1) {
        if (t < off) s[t] += s[t + off];
        __syncthreads();
    }
    if (t == 0) partials[b] = s[0];
}

__global__ __launch_bounds__(512) void k_scanB(const int* __restrict__ partials,
                                               int* __restrict__ base,
                                               int* __restrict__ off_n, int nb) {
    __shared__ int s[512];
    int t = threadIdx.x;
    int v = (t < nb) ? partials[t] : 0;
    s[t] = v;
    __syncthreads();
    for (int off = 1; off < 512; off <<= 1) {
        int x = (t >= off) ? s[t - off] : 0;
        __syncthreads();
        s[t] += x;
        __syncthreads();
    }
    if (t < nb) base[t] = s[t] - v;          // exclusive
    if (t == nb - 1) off_n[0] = s[t];        // total = offsets[N]
}

__global__ __launch_bounds__(256) void k_scanC(const int* __restrict__ cnt,
                                               const int* __restrict__ base,
                                               int* __restrict__ offsets, int n) {
    __shared__ int s[256];
    int b = blockIdx.x, t = threadIdx.x;
    int i0 = b * 512 + t * 2;
    int v0 = (i0 < n) ? cnt[i0] : 0;
    int v1 = (i0 + 1 < n) ? cnt[i0 + 1] : 0;
    int sum = v0 + v1;
    s[t] = sum;
    __syncthreads();
    for (int off = 1; off < 256; off <<= 1) {
        int x = (t >= off) ? s[t - off] : 0;
        __syncthreads();
        s[t] += x;
        __syncthreads();
    }
    int excl = s[t] - sum + base[b];
    if (i0 < n) offsets[i0] = excl;
    if (i0 + 1 < n) offsets[i0 + 1] = excl + v0;
}

// packed CSR entry: .x = src, .y = bit-cast float norm; slot = offsets[dst]+rank
__global__ void k_fill(const int* __restrict__ src, const int* __restrict__ dst,
                       const int* __restrict__ rank, const int* __restrict__ offsets,
                       const float* __restrict__ dinv, int2* __restrict__ csr, int e) {
    int i = blockIdx.x * 256 + threadIdx.x;
    if (i < e) {
        int s = src[i];
        int d = dst[i];
        int pos = offsets[d] + rank[i];
        csr[pos] = make_int2(s, __float_as_int(dinv[s] * dinv[d]));
    }
}

// small 128x128 @ 128x128
__global__ __launch_bounds__(128) void k_wmm(const float* __restrict__ A,
                                             const float* __restrict__ B,
                                             float* __restrict__ Cm) {
    __shared__ float a[128];
    int r = blockIdx.x, d = threadIdx.x;
    a[d] = A[r * 128 + d];
    __syncthreads();
    float acc = 0.0f;
#pragma unroll 8
    for (int k = 0; k < 128; k++) acc += a[k] * B[k * 128 + d];
    Cm[r * 128 + d] = acc;
}

// blocks 0..127: row r of Wtot = W1 @ W4, written DIRECTLY as hi/lo MFMA
// B-fragments into pack (k_wpack folded in — Wtot never materialized).
// frag(s,t): lane l, elem j holds W[s*32 + 8*(l>>4) + j][t*16 + (l&15)];
// inverse for (R,C): s=R>>5, j=R&7, l=((R>>3)&3)*16+(C&15), t=C>>4.
// block 128: bias chain -> cmat rows 0..3 = b2 W2^j, row 4 = b1 W4.
__global__ __launch_bounds__(128) void k_wmm_bias(const float* __restrict__ W1,
                                                  const float* __restrict__ W4,
                                                  const float* __restrict__ W2,
                                                  const float* __restrict__ b1,
                                                  const float* __restrict__ b2,
                                                  __half* __restrict__ pack,
                                                  float* __restrict__ cmat) {
    __shared__ float s[128];
    int d = threadIdx.x;
    if (blockIdx.x < 128) {
        int r = blockIdx.x;
        s[d] = W1[r * 128 + d];
        __syncthreads();
        float acc = 0.0f;
#pragma unroll 8
        for (int k = 0; k < 128; k++) acc += s[k] * W4[k * 128 + d];
        // pack slot for element (r, d)
        int ss = r >> 5, j = r & 7;
        int l = ((r >> 3) & 3) * 16 + (d & 15);
        int t = d >> 4;
        int tid = ss * 512 + t * 64 + l;
        __half hh = __float2half(acc);
        float rem = acc - __half2float(hh);
        pack[(size_t)tid * 8 + j] = hh;
        pack[16384 + (size_t)tid * 8 + j] = __float2half(rem);
        return;
    }
    float v = b2[d];
    cmat[d] = v;
    for (int j = 1; j <= 3; j++) {
        s[d] = v;
        __syncthreads();
        float acc = 0.0f;
#pragma unroll 8
        for (int k = 0; k < 128; k++) acc += s[k] * W2[k * 128 + d];
        v = acc;
        cmat[j * 128 + d] = v;
        __syncthreads();
    }
    s[d] = b1[d];
    __syncthreads();
    float acc = 0.0f;
#pragma unroll 8
    for (int k = 0; k < 128; k++) acc += s[k] * W4[k * 128 + d];
    cmat[4 * 128 + d] = acc;
}

// ---------------- matmul: O = Hh(fp16) @ (Whi+Wlo) + const-bias + U C ------
// Pure-register MFMA kernel: no LDS, no syncthreads. 4 waves/block, each wave
// 16 rows x 128 cols. W fragments from L2-resident pack buffer.
__global__ __launch_bounds__(256) void k_matmul(const __half* __restrict__ Hh,
                                                const __half* __restrict__ Wpack,
                                                float* __restrict__ O,
                                                const float* __restrict__ ucol,  // [4][n]
                                                const float* __restrict__ cmat,  // [5][128]
                                                int nrows) {
    const int t = threadIdx.x;
    const int lane = t & 63, wave = t >> 6;
    const int rows0 = blockIdx.x * 64 + wave * 16;
    const int lrow = lane & 15, lk = lane >> 4;

    // epilogue u values for this lane's 4 output rows
    float uu[4][4];
#pragma unroll
    for (int r = 0; r < 4; r++) {
        int row = rows0 + lk * 4 + r;
        if (row >= nrows) row = nrows - 1;     // clamped rows never stored
#pragma unroll
        for (int tt = 0; tt < 4; tt++) uu[tt][r] = ucol[(size_t)tt * nrows + row];
    }

    floatx4 acc[8];
#pragma unroll
    for (int tl = 0; tl < 8; tl++) {
        int col = tl * 16 + lrow;
        float c0 = cmat[col];
        float c1 = cmat[128 + col], c2 = cmat[256 + col];
        float c3 = cmat[384 + col], c4 = cmat[512 + col];
#pragma unroll
        for (int r = 0; r < 4; r++)
            acc[tl][r] = c0 + uu[0][r] * c1 + uu[1][r] * c2
                            + uu[2][r] * c3 + uu[3][r] * c4;
    }

    int arow = rows0 + lrow;
    if (arow >= nrows) arow = nrows - 1;       // feeds only unstored D-rows
    const __half* abase = Hh + (size_t)arow * 128 + lk * 8;

#pragma unroll
    for (int s = 0; s < 4; s++) {
        half8 a = *reinterpret_cast<const half8*>(abase + s * 32);
        const __half* wb = Wpack + (size_t)s * 4096 + (size_t)lane * 8;
#pragma unroll
        for (int tl = 0; tl < 8; tl++) {
            half8 bh = *reinterpret_cast<const half8*>(wb + (size_t)tl * 512);
            half8 bl = *reinterpret_cast<const half8*>(wb + (size_t)tl * 512 + 16384);
            acc[tl] = __builtin_amdgcn_mfma_f32_16x16x32_f16(a, bh, acc[tl], 0, 0, 0);
            acc[tl] = __builtin_amdgcn_mfma_f32_16x16x32_f16(a, bl, acc[tl], 0, 0, 0);
        }
    }

    // C/D layout (HW-verified): col = lane&15, row = (lane>>4)*4 + reg
#pragma unroll
    for (int r = 0; r < 4; r++) {
        int row = rows0 + lk * 4 + r;
        if (row < nrows) {
            float* orow = O + (size_t)row * 128 + lrow;
#pragma unroll
            for (int tl = 0; tl < 8; tl++) orow[tl * 16] = acc[tl][r];
        }
    }
}

// ---------------- gather: O = A T (+ optional fused u_out = A u_in) --------
// Row-major fp16 rows (256B): half-wave per row = 32 lanes x 8B; 8-edge main
// loop = 4 independent dual-row loads in flight (VGPR ~28, ~76% occupancy —
// the measured-optimal geometry; both XCD-sliced variants r8/r9 regressed).
template <bool WITH_U, bool IN_F16, bool OUT_F16>
__global__ __launch_bounds__(256) void k_gather(const void* __restrict__ Tv,
                                                const int2* __restrict__ csr,
                                                const int* __restrict__ offsets,
                                                const float* __restrict__ dinv,
                                                void* __restrict__ Ov,
                                                const float* __restrict__ uin,
                                                float* __restrict__ uout, int n) {
    int node = blockIdx.x * 4 + (threadIdx.x >> 6);
    if (node >= n) return;
    int lane = threadIdx.x & 63;
    int hf = lane >> 5;              // 0 or 1
    int c = (lane & 31) << 2;        // col base (4 cols)
    const __half* Tch = (const __half*)Tv + c;
    const float*  Tcf = (const float*)Tv + c;

    float ax = 0.f, ay = 0.f, az = 0.f, aw = 0.f;
    float uacc = 0.f;
    if (hf == 0) {
        float di = dinv[node];
        float sw = 2.0f * di * di;
        if (IN_F16) {
            uint2 raw = *(const uint2*)(Tch + (size_t)node * D);
            acc_h4(ax, ay, az, aw, sw, raw);
        } else {
            float4 v = *(const float4*)(Tcf + (size_t)node * D);
            ax = sw * v.x; ay = sw * v.y; az = sw * v.z; aw = sw * v.w;
        }
        if (WITH_U) uacc = sw * (uin ? uin[node] : 1.0f);
    }

    int e = offsets[node];
    const int e1 = offsets[node + 1];

    for (; e + 8 <= e1; e += 8) {
        int2 p0 = csr[e + hf];
        int2 p1 = csr[e + 2 + hf];
        int2 p2 = csr[e + 4 + hf];
        int2 p3 = csr[e + 6 + hf];
        float w0 = __int_as_float(p0.y), w1 = __int_as_float(p1.y);
        float w2 = __int_as_float(p2.y), w3 = __int_as_float(p3.y);
        if (IN_F16) {
            uint2 r0 = *(const uint2*)(Tch + (size_t)p0.x * D);
            uint2 r1 = *(const uint2*)(Tch + (size_t)p1.x * D);
            uint2 r2 = *(const uint2*)(Tch + (size_t)p2.x * D);
            uint2 r3 = *(const uint2*)(Tch + (size_t)p3.x * D);
            if (WITH_U) {
                if (uin) {
                    uacc += w0 * uin[p0.x] + w1 * uin[p1.x]
                          + w2 * uin[p2.x] + w3 * uin[p3.x];
                } else {
                    uacc += w0 + w1 + w2 + w3;
                }
            }
            acc_h4(ax, ay, az, aw, w0, r0);
            acc_h4(ax, ay, az, aw, w1, r1);
            acc_h4(ax, ay, az, aw, w2, r2);
            acc_h4(ax, ay, az, aw, w3, r3);
        } else {
            float4 v0 = *(const float4*)(Tcf + (size_t)p0.x * D);
            float4 v1 = *(const float4*)(Tcf + (size_t)p1.x * D);
            float4 v2 = *(const float4*)(Tcf + (size_t)p2.x * D);
            float4 v3 = *(const float4*)(Tcf + (size_t)p3.x * D);
            if (WITH_U) {
                if (uin) {
                    uacc += w0 * uin[p0.x] + w1 * uin[p1.x]
                          + w2 * uin[p2.x] + w3 * uin[p3.x];
                } else {
                    uacc += w0 + w1 + w2 + w3;
                }
            }
            ax += w0 * v0.x; ay += w0 * v0.y; az += w0 * v0.z; aw += w0 * v0.w;
            ax += w1 * v1.x; ay += w1 * v1.y; az += w1 * v1.z; aw += w1 * v1.w;
            ax += w2 * v2.x; ay += w2 * v2.y; az += w2 * v2.z; aw += w2 * v2.w;
            ax += w3 * v3.x; ay += w3 * v3.y; az += w3 * v3.z; aw += w3 * v3.w;
        }
    }
    for (; e + 2 <= e1; e += 2) {
        int2 p0 = csr[e + hf];
        float w0 = __int_as_float(p0.y);
        if (WITH_U) uacc += w0 * (uin ? uin[p0.x] : 1.0f);
        if (IN_F16) {
            uint2 r0 = *(const uint2*)(Tch + (size_t)p0.x * D);
            acc_h4(ax, ay, az, aw, w0, r0);
        } else {
            float4 v0 = *(const float4*)(Tcf + (size_t)p0.x * D);
            ax += w0 * v0.x; ay += w0 * v0.y; az += w0 * v0.z; aw += w0 * v0.w;
        }
    }
    if (e < e1 && hf == 0) {
        int2 p0 = csr[e];
        float w0 = __int_as_float(p0.y);
        if (WITH_U) uacc += w0 * (uin ? uin[p0.x] : 1.0f);
        if (IN_F16) {
            uint2 r0 = *(const uint2*)(Tch + (size_t)p0.x * D);
            acc_h4(ax, ay, az, aw, w0, r0);
        } else {
            float4 v0 = *(const float4*)(Tcf + (size_t)p0.x * D);
            ax += w0 * v0.x; ay += w0 * v0.y; az += w0 * v0.z; aw += w0 * v0.w;
        }
    }

    ax += __shfl_xor(ax, 32, 64);
    ay += __shfl_xor(ay, 32, 64);
    az += __shfl_xor(az, 32, 64);
    aw += __shfl_xor(aw, 32, 64);
    if (WITH_U) uacc += __shfl_xor(uacc, 32, 64);

    if (hf == 0) {
        if (OUT_F16) {
            __half2 o01 = __float22half2_rn(make_float2(ax, ay));
            __half2 o23 = __float22half2_rn(make_float2(az, aw));
            float2 raw;
            *(__half2*)&raw.x = o01;
            *(__half2*)&raw.y = o23;
            *(float2*)((__half*)Ov + (size_t)node * D + c) = raw;
        } else {
            *(float4*)((float*)Ov + (size_t)node * D + c) =
                make_float4(ax, ay, az, aw);
        }
        if (WITH_U && lane == 0) uout[node] = uacc;
    }
}

// ---------------- launch ----------------
// out = (A^5 x)(W1 W2^4) + b2 + sum_{j=1..3}(A^j 1)(b2 W2^j) + (A^4 1)(b1 W2^4)
// Intermediates fp16 row-major (f32 accumulate); MFMA matmul, W hi/lo split.

extern "C" void kernel_launch(void* const* d_in, const int* in_sizes, int n_in,
                              void* d_out, int out_size, void* d_ws, size_t ws_size,
                              hipStream_t stream) {
    const float* x  = (const float*)d_in[0];
    const int*   ei = (const int*)d_in[1];
    const float* W1 = (const float*)d_in[2];
    const float* b1 = (const float*)d_in[3];
    const float* W2 = (const float*)d_in[4];
    const float* b2 = (const float*)d_in[5];
    const int N = in_sizes[0] / D;
    const int E = in_sizes[1] / 2;
    float* out = (float*)d_out;

    char* ws = (char*)d_ws;
    size_t woff = 0;
    auto alloc = [&](size_t bytes) -> void* {
        void* p = ws + woff;
        woff = (woff + bytes + 15) & ~(size_t)15;
        return p;
    };
    __half* T16a    = (__half*)alloc((size_t)N * D * sizeof(__half));
    __half* T16b    = (__half*)alloc((size_t)N * D * sizeof(__half));
    int*   cnt      = (int*)  alloc((size_t)N * sizeof(int));
    int*   offsets  = (int*)  alloc((size_t)(N + 1) * sizeof(int));
    int*   rank     = (int*)  alloc((size_t)E * sizeof(int));
    float* dinv     = (float*)alloc((size_t)N * sizeof(float));
    int2*  csr      = (int2*) alloc((size_t)E * sizeof(int2));
    int*   partials = (int*)  alloc(1024 * sizeof(int));
    int*   base     = (int*)  alloc(1024 * sizeof(int));
    float* ucol     = (float*)alloc((size_t)4 * N * sizeof(float));   // [4][N]
    float* cmat     = (float*)alloc(5 * 128 * sizeof(float));         // [5][128]
    float* Wsq      = (float*)alloc(128 * 128 * sizeof(float));
    float* W4       = (float*)alloc(128 * 128 * sizeof(float));
    __half* Wpack   = (__half*)alloc(32768 * sizeof(__half));         // hi|lo frags
    size_t x16_bytes = (size_t)N * D * sizeof(__half);
    bool use_x16 = (woff + x16_bytes) <= ws_size;
    __half* X16 = use_x16 ? (__half*)alloc(x16_bytes) : nullptr;
    (void)n_in; (void)out_size;

    const int* e_src = ei;
    const int* e_dst = ei + E;
    const int NB = (N + 511) / 512;

    // --- CSR build (rank-based, no atomic in fill) ---
    k_zero<<<(N + 255) / 256, 256, 0, stream>>>(cnt, N);
    k_count<<<(E + 255) / 256, 256, 0, stream>>>(e_dst, cnt, rank, E);
    k_scanA<<<NB, 256, 0, stream>>>(cnt, partials, dinv, N);
    k_scanB<<<1, 512, 0, stream>>>(partials, base, offsets + N, NB);
    k_scanC<<<NB, 256, 0, stream>>>(cnt, base, offsets, N);
    k_fill<<<(E + 255) / 256, 256, 0, stream>>>(e_src, e_dst, rank, offsets,
                                                dinv, csr, E);

    // --- g = A^5 x (fp16 ping-pong); u_j = A^j 1 fused into gathers 1-4 ---
    const int GG = (N + 3) / 4;
    if (use_x16) {
        int n8 = (N * D) / 8;
        k_f2h<<<(n8 + 255) / 256, 256, 0, stream>>>(x, X16, n8);
        k_gather<true, true, true><<<GG, 256, 0, stream>>>(
            X16, csr, offsets, dinv, T16a, nullptr, ucol, N);
    } else {
        k_gather<true, false, true><<<GG, 256, 0, stream>>>(
            x, csr, offsets, dinv, T16a, nullptr, ucol, N);
    }
    k_gather<true,  true, true><<<GG, 256, 0, stream>>>(
        T16a, csr, offsets, dinv, T16b, ucol,         ucol + N,     N);
    k_gather<true,  true, true><<<GG, 256, 0, stream>>>(
        T16b, csr, offsets, dinv, T16a, ucol + N,     ucol + 2 * N, N);
    k_gather<true,  true, true><<<GG, 256, 0, stream>>>(
        T16a, csr, offsets, dinv, T16b, ucol + 2 * N, ucol + 3 * N, N);
    k_gather<false, true, true><<<GG, 256, 0, stream>>>(
        T16b, csr, offsets, dinv, T16a, nullptr,      nullptr,      N);

    // --- weight chain: Wsq = W2^2, W4 = W2^4, then
    //     [Wtot = W1 W4 -> packed hi/lo MFMA frags  ||  bias chain] ---
    k_wmm<<<128, 128, 0, stream>>>(W2, W2, Wsq);
    k_wmm<<<128, 128, 0, stream>>>(Wsq, Wsq, W4);
    k_wmm_bias<<<129, 128, 0, stream>>>(W1, W4, W2, b1, b2, Wpack, cmat);

    // --- out = T16a @ Wtot + b2 + U C  (MFMA) ---
    k_matmul<<<(N + 63) / 64, 256, 0, stream>>>(T16a, Wpack, out, ucol, cmat, N);
}